// Round 5
// baseline (785.568 us; speedup 1.0000x reference)
//
// Round 5: split-phase schedule, per-wave flags, 1 barrier/step.
// A: l1(t) -> publish h1(t).  B: l2(t-1) (reuses h1(t-1) frags from A) -> publish h2(t-1).
// One vmcnt(0) + per-wave flag; group poll (64 flags) subsumes intra-WG ordering.
// C: readback h1(t)/h2(t-1) -> LDS, x(t+1) pack; single __syncthreads; distributed fc.
#include <hip/hip_runtime.h>

typedef unsigned short u16;
typedef unsigned int   u32;
typedef __attribute__((ext_vector_type(8))) short bf16x8;  // 8 bf16 (4 VGPRs)
typedef __attribute__((ext_vector_type(4))) float f32x4;   // MFMA C/D frag

#define DEVINL static __device__ __forceinline__
#define MFMA __builtin_amdgcn_mfma_f32_16x16x32_bf16

DEVINL u16 f2bf(float f){ u32 x = __float_as_uint(f); return (u16)((x + 0x7fffu + ((x>>16)&1u)) >> 16); }
DEVINL float bf2f(u16 u){ return __uint_as_float(((u32)u) << 16); }
DEVINL u32 pack2(float a, float b){ return (u32)f2bf(a) | ((u32)f2bf(b) << 16); }
DEVINL float sigm(float x){ return 1.f/(1.f + __expf(-x)); }
DEVINL float tanhs(float x){ float xc = fminf(fmaxf(x,-15.f),15.f); float e = __expf(2.f*xc); return (e-1.f)/(e+1.f); }
DEVINL void g_store(u32* p, u32 v){ __hip_atomic_store(p, v, __ATOMIC_RELAXED, __HIP_MEMORY_SCOPE_AGENT); }
DEVINL u32  g_load(const u32* p){ return __hip_atomic_load(p, __ATOMIC_RELAXED, __HIP_MEMORY_SCOPE_AGENT); }

// ---------------- prep: pack weights to bf16 with row permutation j' = u*4+gate
// matrix order m: 0 eIH_l0, 1 eHH_l0, 2 eIH_l1, 3 eHH_l1, 4 dIH_l0, 5 dHH_l0, 6 dIH_l1, 7 dHH_l1
__global__ void pack_all(const float* __restrict__ eih, const float* __restrict__ ehh,
                         const float* __restrict__ dih, const float* __restrict__ dhh,
                         const float* __restrict__ ebi, const float* __restrict__ ebh,
                         const float* __restrict__ dbi, const float* __restrict__ dbh,
                         u16* __restrict__ wout, float* __restrict__ bout,
                         u32* __restrict__ flags){
  int blk = blockIdx.x, t = threadIdx.x;
  if (blk < 8192){
    int m = blk >> 10, j2 = blk & 1023;
    const float* base = (m < 4) ? ((m & 1) ? ehh : eih) : ((m & 1) ? dhh : dih);
    const float* S = base + (size_t)((m >> 1) & 1) * 262144;  // layer select
    int u = j2 >> 2, g = j2 & 3, j = g*256 + u;
    wout[(size_t)blk*256 + t] = f2bf(S[(size_t)j*256 + t]);
  } else if (blk < 8208){
    int idx = (blk - 8192)*256 + t;             // 0..4095 : [phase][layer][j']
    int phase = idx >> 11, l = (idx >> 10) & 1, j2 = idx & 1023;
    int u = j2 >> 2, g = j2 & 3, j = g*256 + u;
    const float* bi = phase ? dbi : ebi;
    const float* bh = phase ? dbh : ebh;
    bout[idx] = bi[l*1024 + j] + bh[l*1024 + j];
  } else {
    for (int i = t; i < 2048; i += 256) flags[i] = 0u;   // flag reset EVERY call
  }
}

struct SM {
  u16   A1[16][520];      // [x(t) 0..255 | h1 256..511]
  u16   A2[16][264];      // [h2 0..255]
  float fcw[4][256];
  float fcb[4];
  int   tok[63][16];
};

__global__ void __launch_bounds__(512, 2)
lstm_main(const int* __restrict__ src, const float* __restrict__ enc_emb,
          const float* __restrict__ dec_emb, const u16* __restrict__ wpack,
          const float* __restrict__ bpack, const float* __restrict__ fcW,
          const float* __restrict__ fcb, float* __restrict__ out,
          u32* __restrict__ H1, u32* __restrict__ H2, u32* __restrict__ flags)
{
  __shared__ SM sm;
  const int tid  = threadIdx.x;
  const int wv   = tid >> 6;          // wave 0..7
  const int lane = tid & 63;
  const int agrp = lane >> 4;         // k-group
  const int n    = lane & 15;         // batch row
  const int gid  = blockIdx.x & 31;   // batch group (same XCD across slices)
  const int w    = blockIdx.x >> 5;   // column-slice 0..7
  const int wgb0 = gid << 4;
  const int xr   = tid >> 5, xc = (tid & 31) << 3;      // x-gather: row, col8
  const int jrow = (w << 7) + (wv << 4) + n;            // permuted gate row j'
  const int uu   = (w << 5) + (wv << 2) + agrp;         // unit owned by lane
  const int pw   = (w << 4) + (wv << 1) + (agrp >> 1);  // u32 word in H slice

  // ---- prologue staging
  for (int i = tid; i < 1008; i += 512){
    int s = i >> 4, b = i & 15;
    int t = (s < 31) ? (31 - s) : (s - 31);   // enc reversed, then dec forward
    sm.tok[s][b] = src[t*512 + wgb0 + b];
  }
  for (int i = tid; i < 1024; i += 512) ((float*)sm.fcw)[i] = fcW[i];
  if (tid < 4) sm.fcb[tid] = fcb[tid];
  for (int i = tid; i < 2048; i += 512){              // zero h1, h2
    int r = i >> 7, p = i & 127;
    *(u32*)&sm.A1[r][256 + (p << 1)] = 0u;
    *(u32*)&sm.A2[r][p << 1] = 0u;
  }
  __syncthreads();
  { // x(0)
    int tk = sm.tok[0][xr];
    const float* e = enc_emb + (size_t)tk*256 + xc;
    float4 v0 = *(const float4*)e, v1 = *(const float4*)(e + 4);
    u32* d = (u32*)&sm.A1[xr][xc];
    d[0]=pack2(v0.x,v0.y); d[1]=pack2(v0.z,v0.w); d[2]=pack2(v1.x,v1.y); d[3]=pack2(v1.z,v1.w);
  }

  // ---- weight-stationary registers: W[2][16] = 128 VGPR + 8 bias
  bf16x8 W[2][16];
  float4 br[2];
  float  c1 = 0.f, c2s = 0.f;

  auto LOADW_L = [&](int ph, int l){
    const u16* base = wpack + (size_t)ph * 1048576;
    #pragma unroll
    for (int kk = 0; kk < 16; kk++){
      const u16* mp = base + (size_t)((l << 1) + (kk >> 3))*262144
                    + (size_t)jrow*256 + ((kk & 7) << 5) + (agrp << 3);
      W[l][kk] = *(const bf16x8*)mp;
    }
    br[l] = *(const float4*)(bpack + (((ph << 1) + l) << 10) + (uu << 2));
  };
  LOADW_L(0, 0); LOADW_L(0, 1);
  __syncthreads();

  auto step = [&](int t, bool doA){
    bf16x8 hf[8];                         // h1(t-1) fragments (A1 hi)
    // ---------- Phase A: l1(t)
    if (doA){
      f32x4 a1 = {0.f,0.f,0.f,0.f};
      #pragma unroll
      for (int kk = 0; kk < 8; kk++){
        bf16x8 bx = *(const bf16x8*)&sm.A1[n][(kk << 5) + (agrp << 3)];
        a1 = MFMA(W[0][kk], bx, a1, 0, 0, 0);
      }
      #pragma unroll
      for (int kk = 0; kk < 8; kk++){
        hf[kk] = *(const bf16x8*)&sm.A1[n][256 + (kk << 5) + (agrp << 3)];
        a1 = MFMA(W[0][8 + kk], hf[kk], a1, 0, 0, 0);
      }
      float I = sigm(a1[0] + br[0].x), F = sigm(a1[1] + br[0].y);
      float G = tanhs(a1[2] + br[0].z), O = sigm(a1[3] + br[0].w);
      float cn = F*c1 + I*G; c1 = cn;
      u16 hb = f2bf(O * tanhs(cn));
      u32 other = (u32)__shfl_xor((int)(u32)hb, 16);
      if ((agrp & 1) == 0)
        g_store(H1 + ((size_t)(t & 1)*32 + gid)*2048 + n*128 + pw, (u32)hb | (other << 16));
    } else {
      #pragma unroll
      for (int kk = 0; kk < 8; kk++)
        hf[kk] = *(const bf16x8*)&sm.A1[n][256 + (kk << 5) + (agrp << 3)];
    }
    // ---------- Phase B: l2(t-1)  (h1(t-1) from hf regs, h2(t-2) from A2)
    if (t > 0){
      f32x4 a2 = {0.f,0.f,0.f,0.f};
      #pragma unroll
      for (int kk = 0; kk < 8; kk++)
        a2 = MFMA(W[1][kk], hf[kk], a2, 0, 0, 0);
      #pragma unroll
      for (int kk = 0; kk < 8; kk++){
        bf16x8 b2 = *(const bf16x8*)&sm.A2[n][(kk << 5) + (agrp << 3)];
        a2 = MFMA(W[1][8 + kk], b2, a2, 0, 0, 0);
      }
      float I = sigm(a2[0] + br[1].x), F = sigm(a2[1] + br[1].y);
      float G = tanhs(a2[2] + br[1].z), O = sigm(a2[3] + br[1].w);
      float cn = F*c2s + I*G; c2s = cn;
      u16 hb = f2bf(O * tanhs(cn));
      u32 other = (u32)__shfl_xor((int)(u32)hb, 16);
      if ((agrp & 1) == 0)
        g_store(H2 + ((size_t)((t - 1) & 1)*32 + gid)*2048 + n*128 + pw, (u32)hb | (other << 16));
    }
    // ---------- per-wave flag: all h1(t)/h2(t-1) stores of THIS wave are visible
    asm volatile("s_waitcnt vmcnt(0)" ::: "memory");
    if (lane == 0) g_store(&flags[(gid << 6) + (w << 3) + wv], (u32)(t + 1));
    // ---------- Phase C: x(t+1) gather (overlaps poll), poll, readback
    const bool hasx = doA && (t + 1) < 63;
    float4 xv0, xv1;
    if (hasx){
      int tk = sm.tok[t+1][xr];
      const float* e = ((t+1) < 31 ? enc_emb : dec_emb) + (size_t)tk*256 + xc;
      xv0 = *(const float4*)e; xv1 = *(const float4*)(e + 4);
    }
    {
      const u32 tgt = (u32)(t + 1);
      for (;;){
        u32 v = g_load(&flags[(gid << 6) + lane]);
        if (__all((int)(v >= tgt))) break;
        __builtin_amdgcn_s_sleep(1);
      }
    }
    {
      const int q = tid << 2, r = tid >> 5, p = q & 127;
      if (doA){
        const u32* h1r = H1 + ((size_t)(t & 1)*32 + gid)*2048;
        u32 v0 = g_load(h1r+q), v1 = g_load(h1r+q+1), v2 = g_load(h1r+q+2), v3 = g_load(h1r+q+3);
        u32* d1 = (u32*)&sm.A1[r][256 + (p << 1)];
        d1[0]=v0; d1[1]=v1; d1[2]=v2; d1[3]=v3;
      }
      if (t > 0){
        const u32* h2r = H2 + ((size_t)((t - 1) & 1)*32 + gid)*2048;
        u32 w0 = g_load(h2r+q), w1 = g_load(h2r+q+1), w2 = g_load(h2r+q+2), w3 = g_load(h2r+q+3);
        u32* d2 = (u32*)&sm.A2[r][p << 1];
        d2[0]=w0; d2[1]=w1; d2[2]=w2; d2[3]=w3;
      }
      if (hasx){
        u32* d = (u32*)&sm.A1[xr][xc];
        d[0]=pack2(xv0.x,xv0.y); d[1]=pack2(xv0.z,xv0.w);
        d[2]=pack2(xv1.x,xv1.y); d[3]=pack2(xv1.z,xv1.w);
      }
    }
    __syncthreads();                                    // SD: LDS writes -> next reads
    // ---------- fc + log_softmax for h2(t-1) (now in A2), rows 2w..2w+1, 2 waves
    if (t >= 32 && tid < 128){
      const int b = (w << 1) + (tid >> 6), v = (tid >> 4) & 3, q16 = tid & 15;
      const u16* hrow = &sm.A2[b][q16 << 4];
      const float* wr = &sm.fcw[v][q16 << 4];
      bf16x8 h0 = *(const bf16x8*)hrow, h1v = *(const bf16x8*)(hrow + 8);
      float s = 0.f;
      #pragma unroll
      for (int e = 0; e < 8; e++){
        s += bf2f((u16)h0[e]) * wr[e];
        s += bf2f((u16)h1v[e]) * wr[8 + e];
      }
      s += __shfl_xor(s, 1); s += __shfl_xor(s, 2);
      s += __shfl_xor(s, 4); s += __shfl_xor(s, 8);
      s += sm.fcb[v];
      float m = fmaxf(s, __shfl_xor(s, 16)); m = fmaxf(m, __shfl_xor(m, 32));
      float e_ = __expf(s - m);
      float es = e_ + __shfl_xor(e_, 16); es += __shfl_xor(es, 32);
      if (q16 == 0)
        out[((size_t)(t - 32)*512 + wgb0 + b)*4 + v] = s - m - __logf(es);
    }
  };

  for (int t = 0; t <= 30; ++t) step(t, true);
  LOADW_L(1, 0);            // dec W1 (l1(31) is first decoder step; l2(30) still enc)
  step(31, true);
  LOADW_L(1, 1);            // dec W2 (first used by l2(31) at step 32)
  for (int t = 32; t <= 62; ++t) step(t, true);
  step(63, false);          // tail: l2(62) + fc(62) -> out row 31
}

extern "C" void kernel_launch(void* const* d_in, const int* in_sizes, int n_in,
                              void* d_out, int out_size, void* d_ws, size_t ws_size,
                              hipStream_t stream){
  const int*   src     = (const int*)  d_in[0];
  const float* enc_emb = (const float*)d_in[2];
  const float* enc_Wih = (const float*)d_in[3];
  const float* enc_Whh = (const float*)d_in[4];
  const float* enc_bih = (const float*)d_in[5];
  const float* enc_bhh = (const float*)d_in[6];
  const float* dec_emb = (const float*)d_in[7];
  const float* dec_Wih = (const float*)d_in[8];
  const float* dec_Whh = (const float*)d_in[9];
  const float* dec_bih = (const float*)d_in[10];
  const float* dec_bhh = (const float*)d_in[11];
  const float* fcW     = (const float*)d_in[12];
  const float* fcb     = (const float*)d_in[13];
  float* out = (float*)d_out;
  (void)in_sizes; (void)n_in; (void)out_size; (void)ws_size;

  // ws: wpack 4MB | bpack 16KB | H1 512KB (2-parity) | H2 512KB | flags 8KB
  u16*   wpack = (u16*)d_ws;
  float* bpack = (float*)((char*)d_ws + 4194304);
  u32*   H1    = (u32*)((char*)d_ws + 4194304 + 16384);
  u32*   H2    = (u32*)((char*)d_ws + 4194304 + 16384 + 524288);
  u32*   flags = (u32*)((char*)d_ws + 4194304 + 16384 + 1048576);

  pack_all<<<8209, 256, 0, stream>>>(enc_Wih, enc_Whh, dec_Wih, dec_Whh,
                                     enc_bih, enc_bhh, dec_bih, dec_bhh,
                                     wpack, bpack, flags);
  lstm_main<<<256, 512, 0, stream>>>(src, enc_emb, dec_emb, wpack, bpack,
                                     fcW, fcb, out, H1, H2, flags);
}